// Round 3
// baseline (134.123 us; speedup 1.0000x reference)
//
#include <hip/hip_runtime.h>
#include <hip/hip_bf16.h>
#include <stdint.h>

typedef __attribute__((ext_vector_type(8))) short bf16x8;
typedef __attribute__((ext_vector_type(4))) float f32x4;

#define NPOS 256
#define NROW 512
#define NCH  256

// ---------------------------------------------------------------------------
// Kernel 1: repack fp32 [i][c][p] -> bf16 X[p][i][c]   (LDS tile transpose)
// ---------------------------------------------------------------------------
__global__ __launch_bounds__(256) void k_repack(const float* __restrict__ src,
                                                const float* __restrict__ tgt,
                                                unsigned short* __restrict__ X) {
  __shared__ float tile[64 * 65];  // [c][p], +1 pad
  int bx = blockIdx.x;
  int i  = bx >> 4;
  int cb = (bx >> 2) & 3;
  int pb = bx & 3;
  int c0 = cb * 64, p0 = pb * 64;
  const float* base = (i < 256) ? (src + (size_t)i * 65536)
                                : (tgt + (size_t)(i - 256) * 65536);
  int t = threadIdx.x;
#pragma unroll
  for (int it = 0; it < 4; ++it) {
    int idx = it * 256 + t;
    int cl = idx >> 4, pq = idx & 15;                // float4 along p (coalesced)
    float4 v = *(const float4*)&base[(c0 + cl) * 256 + p0 + pq * 4];
    tile[cl * 65 + pq * 4 + 0] = v.x;
    tile[cl * 65 + pq * 4 + 1] = v.y;
    tile[cl * 65 + pq * 4 + 2] = v.z;
    tile[cl * 65 + pq * 4 + 3] = v.w;
  }
  __syncthreads();
#pragma unroll
  for (int it = 0; it < 4; ++it) {
    int idx = it * 256 + t;
    int pl = idx >> 4, cq = idx & 15;                // ushort4 along c (coalesced)
    ushort4 o;
    unsigned short* op = &o.x;
#pragma unroll
    for (int j = 0; j < 4; ++j) {
      unsigned u = __float_as_uint(tile[(cq * 4 + j) * 65 + pl]);
      op[j] = (unsigned short)((u + 0x7fffu + ((u >> 16) & 1u)) >> 16);  // RNE
    }
    *(ushort4*)&X[((size_t)(p0 + pl) * NROW + i) * NCH + c0 + cq * 4] = o;
  }
}

// ---------------------------------------------------------------------------
// Kernel 2: SQ[p*512+i] = sum_c X[p][i][c]^2
// ---------------------------------------------------------------------------
__global__ __launch_bounds__(256) void k_sq(const unsigned short* __restrict__ X,
                                            float* __restrict__ SQ) {
  int gid = blockIdx.x * 256 + threadIdx.x;
  int row = gid >> 5;
  int l = threadIdx.x & 31;
  uint4 v = *(const uint4*)(X + (size_t)row * NCH + l * 8);
  float s = 0.f;
  const unsigned* u = &v.x;
#pragma unroll
  for (int j = 0; j < 4; ++j) {
    float flo = __uint_as_float(u[j] << 16);
    float fhi = __uint_as_float(u[j] & 0xffff0000u);
    s += flo * flo + fhi * fhi;
  }
#pragma unroll
  for (int off = 16; off; off >>= 1) s += __shfl_down(s, off, 32);
  if (l == 0) SQ[row] = s;
}

// ---------------------------------------------------------------------------
// Kernel 3: register-direct fragment GEMM + RBF epilogue. NO LDS staging,
// NO barriers in the K loop. Fragments gathered per-lane from row-major X:
//   lane l <- X[p][rowblk*16+(l&15)][ks*32+(l>>4)*8 ..+8]  (16 B granule;
//   4 kg-slots of one row are a contiguous 64 B sector -> full sector eff.)
// Gram symmetry: A-frag == B-frag layout, so one loader serves both.
// grid: 256 pos * 10 upper-tri tiles(128x128) = 2560 blocks, 4 waves (2x2).
// Diag tiles: wave (1,0) skipped, wave (0,1) weight 2.
// ---------------------------------------------------------------------------
__global__ __launch_bounds__(256) void k_mmd(const unsigned short* __restrict__ X,
                                             const float* __restrict__ SQ,
                                             float* __restrict__ part) {
  __shared__ float wsum[4];

  int bid = blockIdx.x;
  int bx = (bid & 7) * 320 + (bid >> 3);   // XCD swizzle (bijective: 2560 = 8*320)
  int p = bx / 10;
  int tileid = bx - p * 10;
  int it, jt;
  if (tileid < 4)      { it = 0; jt = tileid; }
  else if (tileid < 7) { it = 1; jt = tileid - 3; }
  else if (tileid < 9) { it = 2; jt = tileid - 5; }
  else                 { it = 3; jt = 3; }
  int i0 = it * 128, j0 = jt * 128;
  int t = threadIdx.x;
  int lane = t & 63, w = t >> 6;
  int wr = w >> 1, wc = w & 1;
  int l15 = lane & 15, lk = lane >> 4;
  bool diag = (it == jt);
  bool skipw = diag && (w == 2);           // mirror of wave (0,1)

  const char* Xp = (const char*)X + (size_t)p * (NROW * NCH) * 2;
  const char* XA = Xp + (size_t)(i0 + wr * 64 + l15) * 512 + lk * 16;
  const char* XB = Xp + (size_t)(j0 + wc * 64 + l15) * 512 + lk * 16;

  f32x4 zero = {0.f, 0.f, 0.f, 0.f};
  f32x4 acc[4][4];
#pragma unroll
  for (int m = 0; m < 4; ++m)
#pragma unroll
    for (int n = 0; n < 4; ++n) acc[m][n] = zero;

  if (!skipw) {
#pragma unroll 2
    for (int ks = 0; ks < 8; ++ks) {
      bf16x8 a[4], b[4];
#pragma unroll
      for (int m = 0; m < 4; ++m)
        a[m] = *(const bf16x8*)(XA + m * 8192 + ks * 64);
#pragma unroll
      for (int n = 0; n < 4; ++n)
        b[n] = *(const bf16x8*)(XB + n * 8192 + ks * 64);
#pragma unroll
      for (int m = 0; m < 4; ++m)
#pragma unroll
        for (int n = 0; n < 4; ++n)
          acc[m][n] = __builtin_amdgcn_mfma_f32_16x16x32_bf16(a[m], b[n], acc[m][n], 0, 0, 0);
    }
  }

  float lsum = 0.f;
  if (!skipw) {
    const float c80 = 0.01803368801f;  // log2(e)/80
    const float* SQp = SQ + p * NROW;
    float sqi[16], sqj[4];
#pragma unroll
    for (int m = 0; m < 4; ++m)
#pragma unroll
      for (int r = 0; r < 4; ++r) sqi[m * 4 + r] = SQp[i0 + wr * 64 + m * 16 + lk * 4 + r];
#pragma unroll
    for (int n = 0; n < 4; ++n) sqj[n] = SQp[j0 + wc * 64 + n * 16 + l15];

    bool sdiag = diag && (wr == wc);       // this wave's 64x64 sits on the self-diagonal
#pragma unroll
    for (int m = 0; m < 4; ++m) {
#pragma unroll
      for (int n = 0; n < 4; ++n) {
#pragma unroll
        for (int r = 0; r < 4; ++r) {
          float cv = acc[m][n][r];
          float D = sqi[m * 4 + r] + sqj[n] - 2.f * cv;
          float e80 = exp2f(-c80 * D);     // exp(-D/80)
          float e40 = e80 * e80;
          float e20 = e40 * e40;
          float e10 = e20 * e20;
          float e5  = e10 * e10;
          float e2  = e5 * e5 * e10;       // exp(-D/2)
          float K = (e80 + e40) + (e20 + e10) + (e5 + e2);
          if (sdiag && m == n) {
            if (lk * 4 + r == l15) K = 6.0f;   // D==0 exactly on the diagonal
          }
          lsum += K;
        }
      }
    }
    if (diag && w == 1) lsum *= 2.0f;      // counts for skipped mirror wave (1,0)
  }
#pragma unroll
  for (int off = 32; off; off >>= 1) lsum += __shfl_down(lsum, off, 64);
  if (lane == 0) wsum[w] = lsum;
  __syncthreads();
  if (t == 0) {
    float sgn = ((it < 2) == (jt < 2)) ? 1.0f : -1.0f;
    float tw  = diag ? 1.0f : 2.0f;        // off-diag tiles count twice (symmetry)
    part[bx] = sgn * tw * (wsum[0] + wsum[1] + wsum[2] + wsum[3]);
  }
}

// ---------------------------------------------------------------------------
// Kernel 4: deterministic final reduce of 2560 partials -> mean
// ---------------------------------------------------------------------------
__global__ __launch_bounds__(256) void k_reduce(const float* __restrict__ part,
                                                float* __restrict__ out) {
  __shared__ float wsum[4];
  int t = threadIdx.x;
  float s = 0.f;
#pragma unroll
  for (int i = 0; i < 10; ++i) s += part[i * 256 + t];
#pragma unroll
  for (int off = 32; off; off >>= 1) s += __shfl_down(s, off, 64);
  int lane = t & 63, w = t >> 6;
  if (lane == 0) wsum[w] = s;
  __syncthreads();
  if (t == 0) out[0] = (wsum[0] + wsum[1] + wsum[2] + wsum[3]) * (1.0f / 16777216.0f);
}

extern "C" void kernel_launch(void* const* d_in, const int* in_sizes, int n_in,
                              void* d_out, int out_size, void* d_ws, size_t ws_size,
                              hipStream_t stream) {
  (void)in_sizes; (void)n_in; (void)out_size; (void)ws_size;
  const float* src = (const float*)d_in[0];
  const float* tgt = (const float*)d_in[1];
  char* ws = (char*)d_ws;
  unsigned short* X = (unsigned short*)ws;                    // 67,108,864 B
  float* SQ   = (float*)(ws + 67108864);                      //    524,288 B
  float* PART = (float*)(ws + 67108864 + 524288);             //     10,240 B

  hipLaunchKernelGGL(k_repack, dim3(8192),  dim3(256), 0, stream, src, tgt, X);
  hipLaunchKernelGGL(k_sq,     dim3(16384), dim3(256), 0, stream, X, SQ);
  hipLaunchKernelGGL(k_mmd,    dim3(2560),  dim3(256), 0, stream, X, SQ, PART);
  hipLaunchKernelGGL(k_reduce, dim3(1),     dim3(256), 0, stream, PART, (float*)d_out);
}

// Round 4
// 93.544 us; speedup vs baseline: 1.4338x; 1.4338x over previous
//
#include <hip/hip_runtime.h>
#include <hip/hip_bf16.h>
#include <stdint.h>

typedef __attribute__((ext_vector_type(8))) short bf16x8;
typedef __attribute__((ext_vector_type(4))) float f32x4;

#define NPOS 256
#define NROW 512
#define NCH  256

// ---------------------------------------------------------------------------
// Kernel 1: repack fp32 [i][c][p] -> bf16 X[p][i][c]   (LDS tile transpose)
// ---------------------------------------------------------------------------
__global__ __launch_bounds__(256) void k_repack(const float* __restrict__ src,
                                                const float* __restrict__ tgt,
                                                unsigned short* __restrict__ X) {
  __shared__ float tile[64 * 65];  // [c][p], +1 pad
  int bx = blockIdx.x;
  int i  = bx >> 4;
  int cb = (bx >> 2) & 3;
  int pb = bx & 3;
  int c0 = cb * 64, p0 = pb * 64;
  const float* base = (i < 256) ? (src + (size_t)i * 65536)
                                : (tgt + (size_t)(i - 256) * 65536);
  int t = threadIdx.x;
#pragma unroll
  for (int it = 0; it < 4; ++it) {
    int idx = it * 256 + t;
    int cl = idx >> 4, pq = idx & 15;                // float4 along p (coalesced)
    float4 v = *(const float4*)&base[(c0 + cl) * 256 + p0 + pq * 4];
    tile[cl * 65 + pq * 4 + 0] = v.x;
    tile[cl * 65 + pq * 4 + 1] = v.y;
    tile[cl * 65 + pq * 4 + 2] = v.z;
    tile[cl * 65 + pq * 4 + 3] = v.w;
  }
  __syncthreads();
#pragma unroll
  for (int it = 0; it < 4; ++it) {
    int idx = it * 256 + t;
    int pl = idx >> 4, cq = idx & 15;                // ushort4 along c (coalesced)
    ushort4 o;
    unsigned short* op = &o.x;
#pragma unroll
    for (int j = 0; j < 4; ++j) {
      unsigned u = __float_as_uint(tile[(cq * 4 + j) * 65 + pl]);
      op[j] = (unsigned short)((u + 0x7fffu + ((u >> 16) & 1u)) >> 16);  // RNE
    }
    *(ushort4*)&X[((size_t)(p0 + pl) * NROW + i) * NCH + c0 + cq * 4] = o;
  }
}

// ---------------------------------------------------------------------------
// Kernel 2: SQ[p*512+i] = sum_c X[p][i][c]^2
// ---------------------------------------------------------------------------
__global__ __launch_bounds__(256) void k_sq(const unsigned short* __restrict__ X,
                                            float* __restrict__ SQ) {
  int gid = blockIdx.x * 256 + threadIdx.x;
  int row = gid >> 5;
  int l = threadIdx.x & 31;
  uint4 v = *(const uint4*)(X + (size_t)row * NCH + l * 8);
  float s = 0.f;
  const unsigned* u = &v.x;
#pragma unroll
  for (int j = 0; j < 4; ++j) {
    float flo = __uint_as_float(u[j] << 16);
    float fhi = __uint_as_float(u[j] & 0xffff0000u);
    s += flo * flo + fhi * fhi;
  }
#pragma unroll
  for (int off = 16; off; off >>= 1) s += __shfl_down(s, off, 32);
  if (l == 0) SQ[row] = s;
}

// ---------------------------------------------------------------------------
// Kernel 3: fused Gram + RBF epilogue, upper-triangle tiles, double-buffered
// 2-phase pipeline: STAGE(kk+1) issued BEFORE compute(kk); ONE barrier per
// kk-step whose implicit vmcnt(0)/lgkmcnt(0) covers both hazards (prefetch
// write->read and read->overwrite). Staging = global_load_lds w=16 with
// linear LDS dest + inverse-swizzled source; reads apply the XOR swizzle.
// grid: 256 pos * 10 tiles(128x128) = 2560 blocks, 4 waves (2x2).
// Diag tiles: wave 2 mirrors wave 1 -> skips compute, wave 1 weight x2.
// ---------------------------------------------------------------------------
__device__ __forceinline__ int swz(int row, int byteoff) {
  return row * 128 + (byteoff ^ ((row & 7) << 4));
}

__global__ __launch_bounds__(256) void k_mmd(const unsigned short* __restrict__ X,
                                             const float* __restrict__ SQ,
                                             float* __restrict__ part) {
  __shared__ unsigned short As[2][128 * 64];
  __shared__ unsigned short Bs[2][128 * 64];
  __shared__ float SQi[128], SQj[128];
  __shared__ float wsum[4];

  int bid = blockIdx.x;
  int bx = (bid & 7) * 320 + (bid >> 3);   // XCD swizzle (bijective: 2560 = 8*320)
  int p = bx / 10;
  int tileid = bx - p * 10;
  int it, jt;
  if (tileid < 4)      { it = 0; jt = tileid; }
  else if (tileid < 7) { it = 1; jt = tileid - 3; }
  else if (tileid < 9) { it = 2; jt = tileid - 5; }
  else                 { it = 3; jt = 3; }
  int i0 = it * 128, j0 = jt * 128;
  int t = threadIdx.x;
  int lane = t & 63, w = t >> 6;
  int wr = w >> 1, wc = w & 1;
  int l15 = lane & 15, lk = lane >> 4;
  bool diag = (it == jt);
  bool skipw = diag && (w == 2);           // mirror of wave (0,1)

  const unsigned short* Xp = X + (size_t)p * (NROW * NCH);
  const char* XA = (const char*)Xp + (size_t)i0 * 512;   // 512 B per row
  const char* XB = (const char*)Xp + (size_t)j0 * 512;

  // per-lane constant source swizzle: row&7 == lane>>3 for every issued chunk
  int lrow = lane >> 3;
  int coff = ((lane & 7) ^ lrow) * 16;

#define STAGE(buf, kk)                                                         \
  {                                                                            \
    _Pragma("unroll")                                                          \
    for (int s = 0; s < 4; ++s) {                                              \
      int rbase = w * 32 + s * 8;                                              \
      const char* ga = XA + (size_t)(rbase + lrow) * 512 + (kk) * 128 + coff;  \
      const char* gb = XB + (size_t)(rbase + lrow) * 512 + (kk) * 128 + coff;  \
      __builtin_amdgcn_global_load_lds(                                        \
          (const __attribute__((address_space(1))) void*)ga,                   \
          (__attribute__((address_space(3))) void*)((char*)&As[buf][0] + rbase * 128), 16, 0, 0); \
      __builtin_amdgcn_global_load_lds(                                        \
          (const __attribute__((address_space(1))) void*)gb,                   \
          (__attribute__((address_space(3))) void*)((char*)&Bs[buf][0] + rbase * 128), 16, 0, 0); \
    }                                                                          \
  }

  STAGE(0, 0);
  if (t < 128) SQi[t] = SQ[p * NROW + i0 + t];
  else         SQj[t - 128] = SQ[p * NROW + j0 + (t - 128)];

  f32x4 zero = {0.f, 0.f, 0.f, 0.f};
  f32x4 acc[4][4];
#pragma unroll
  for (int m = 0; m < 4; ++m)
#pragma unroll
    for (int n = 0; n < 4; ++n) acc[m][n] = zero;

  __syncthreads();   // drain prologue stage

#pragma unroll
  for (int kk = 0; kk < 4; ++kk) {
    if (kk < 3) STAGE((kk + 1) & 1, kk + 1);   // prefetch: in flight during MFMAs
    if (!skipw) {
      const char* Ab = (const char*)&As[kk & 1][0];
      const char* Bb = (const char*)&Bs[kk & 1][0];
#pragma unroll
      for (int ks = 0; ks < 2; ++ks) {
        bf16x8 a[4], b[4];
#pragma unroll
        for (int m = 0; m < 4; ++m)
          a[m] = *(const bf16x8*)(Ab + swz(wr * 64 + m * 16 + l15, ks * 64 + lk * 16));
#pragma unroll
        for (int n = 0; n < 4; ++n)
          b[n] = *(const bf16x8*)(Bb + swz(wc * 64 + n * 16 + l15, ks * 64 + lk * 16));
#pragma unroll
        for (int m = 0; m < 4; ++m)
#pragma unroll
          for (int n = 0; n < 4; ++n)
            acc[m][n] = __builtin_amdgcn_mfma_f32_16x16x32_bf16(a[m], b[n], acc[m][n], 0, 0, 0);
      }
    }
    __syncthreads();   // one barrier per step: drains prefetch vmcnt + read lgkm
  }
#undef STAGE

  float lsum = 0.f;
  if (!skipw) {
    const float c80 = 0.01803368801f;  // log2(e)/80
    float sqi[16], sqj[4];
#pragma unroll
    for (int m = 0; m < 4; ++m)
#pragma unroll
      for (int r = 0; r < 4; ++r) sqi[m * 4 + r] = SQi[wr * 64 + m * 16 + lk * 4 + r];
#pragma unroll
    for (int n = 0; n < 4; ++n) sqj[n] = SQj[wc * 64 + n * 16 + l15];

    bool sdiag = diag && (wr == wc);
#pragma unroll
    for (int m = 0; m < 4; ++m) {
#pragma unroll
      for (int n = 0; n < 4; ++n) {
#pragma unroll
        for (int r = 0; r < 4; ++r) {
          float cv = acc[m][n][r];
          float D = sqi[m * 4 + r] + sqj[n] - 2.f * cv;
          float e80 = exp2f(-c80 * D);     // exp(-D/80)
          float e40 = e80 * e80;
          float e20 = e40 * e40;
          float e10 = e20 * e20;
          float e5  = e10 * e10;
          float e2  = e5 * e5 * e10;       // exp(-D/2)
          float K = (e80 + e40) + (e20 + e10) + (e5 + e2);
          if (sdiag && m == n) {
            if (lk * 4 + r == l15) K = 6.0f;   // exact diagonal: D==0 -> K=6
          }
          lsum += K;
        }
      }
    }
    if (diag && w == 1) lsum *= 2.0f;      // stands in for skipped mirror wave
  }
#pragma unroll
  for (int off = 32; off; off >>= 1) lsum += __shfl_down(lsum, off, 64);
  if (lane == 0) wsum[w] = lsum;
  __syncthreads();
  if (t == 0) {
    float sgn = ((it < 2) == (jt < 2)) ? 1.0f : -1.0f;
    float tw  = diag ? 1.0f : 2.0f;        // off-diag tiles count twice (symmetry)
    part[bx] = sgn * tw * (wsum[0] + wsum[1] + wsum[2] + wsum[3]);
  }
}

// ---------------------------------------------------------------------------
// Kernel 4: deterministic final reduce of 2560 partials -> mean
// ---------------------------------------------------------------------------
__global__ __launch_bounds__(256) void k_reduce(const float* __restrict__ part,
                                                float* __restrict__ out) {
  __shared__ float wsum[4];
  int t = threadIdx.x;
  float s = 0.f;
#pragma unroll
  for (int i = 0; i < 10; ++i) s += part[i * 256 + t];
#pragma unroll
  for (int off = 32; off; off >>= 1) s += __shfl_down(s, off, 64);
  int lane = t & 63, w = t >> 6;
  if (lane == 0) wsum[w] = s;
  __syncthreads();
  if (t == 0) out[0] = (wsum[0] + wsum[1] + wsum[2] + wsum[3]) * (1.0f / 16777216.0f);
}

extern "C" void kernel_launch(void* const* d_in, const int* in_sizes, int n_in,
                              void* d_out, int out_size, void* d_ws, size_t ws_size,
                              hipStream_t stream) {
  (void)in_sizes; (void)n_in; (void)out_size; (void)ws_size;
  const float* src = (const float*)d_in[0];
  const float* tgt = (const float*)d_in[1];
  char* ws = (char*)d_ws;
  unsigned short* X = (unsigned short*)ws;                    // 67,108,864 B
  float* SQ   = (float*)(ws + 67108864);                      //    524,288 B
  float* PART = (float*)(ws + 67108864 + 524288);             //     10,240 B

  hipLaunchKernelGGL(k_repack, dim3(8192),  dim3(256), 0, stream, src, tgt, X);
  hipLaunchKernelGGL(k_sq,     dim3(16384), dim3(256), 0, stream, X, SQ);
  hipLaunchKernelGGL(k_mmd,    dim3(2560),  dim3(256), 0, stream, X, SQ, PART);
  hipLaunchKernelGGL(k_reduce, dim3(1),     dim3(256), 0, stream, PART, (float*)d_out);
}